// Round 1
// baseline (143.061 us; speedup 1.0000x reference)
//
#include <hip/hip_runtime.h>
#include <math.h>

#define NROW 256
#define DIM  65536
#define BM   64
#define BK   32

// ---------------------------------------------------------------------------
// GEMM: G = E * E^T  (256 x 65536) -> (256 x 256), symmetric.
// Grid: (10 tile-pairs, P k-splits). Each block computes a 64x64 tile of
// A_ti * A_tj^T over its k-chunk, writes into its own partial buffer
// (and the transposed mirror when ti != tj). No atomics -> deterministic.
// ---------------------------------------------------------------------------
__global__ __launch_bounds__(256) void gemm_pair(const float* __restrict__ E,
                                                 float* __restrict__ part,
                                                 int Kc) {
    // pair index -> (ti, tj), ti <= tj, 4x4 tiles
    int rem = blockIdx.x, cnt = 4, ti = 0;
    while (rem >= cnt) { rem -= cnt; cnt--; ti++; }
    const int tj = ti + rem;
    const int s  = blockIdx.y;

    const int tid = threadIdx.x;
    const int tx = tid & 15;        // 0..15 -> output cols
    const int ty = tid >> 4;        // 0..15 -> output rows

    __shared__ float As[BK][BM];    // k-major: conflict-free b128 reads
    __shared__ float Bs[BK][BM];

    float acc[4][4] = {};

    const float* Arow = E + (size_t)(ti * BM) * DIM;
    const float* Brow = E + (size_t)(tj * BM) * DIM;
    const int k0 = s * Kc;

    for (int kb = 0; kb < Kc; kb += BK) {
        __syncthreads();   // protect previous iteration's LDS reads
        // stage 64 rows x 32 k per side: 512 float4 / side, 2 per thread
        for (int a = tid; a < 512; a += 256) {
            const int row = a >> 3;          // 0..63
            const int kg  = (a & 7) << 2;    // 0,4,...,28
            const size_t goff = (size_t)row * DIM + k0 + kb + kg;
            const float4 av = *(const float4*)(Arow + goff);
            const float4 bv = *(const float4*)(Brow + goff);
            As[kg+0][row] = av.x; As[kg+1][row] = av.y;
            As[kg+2][row] = av.z; As[kg+3][row] = av.w;
            Bs[kg+0][row] = bv.x; Bs[kg+1][row] = bv.y;
            Bs[kg+2][row] = bv.z; Bs[kg+3][row] = bv.w;
        }
        __syncthreads();
        #pragma unroll
        for (int kk = 0; kk < BK; ++kk) {
            const float4 a4 = *(const float4*)&As[kk][ty * 4];
            const float4 b4 = *(const float4*)&Bs[kk][tx * 4];
            const float ar[4] = {a4.x, a4.y, a4.z, a4.w};
            const float br[4] = {b4.x, b4.y, b4.z, b4.w};
            #pragma unroll
            for (int i2 = 0; i2 < 4; ++i2)
                #pragma unroll
                for (int j2 = 0; j2 < 4; ++j2)
                    acc[i2][j2] += ar[i2] * br[j2];
        }
    }

    float* Pg = part + (size_t)s * (NROW * NROW);
    #pragma unroll
    for (int i2 = 0; i2 < 4; ++i2) {
        const int gi = ti * BM + ty * 4 + i2;
        #pragma unroll
        for (int j2 = 0; j2 < 4; ++j2) {
            const int gj = tj * BM + tx * 4 + j2;
            Pg[gi * NROW + gj] = acc[i2][j2];
            if (ti != tj) Pg[gj * NROW + gi] = acc[i2][j2];
        }
    }
}

// Fixed-order sum of the P partial G buffers -> deterministic.
__global__ __launch_bounds__(256) void reduce_G(const float* __restrict__ part,
                                                float* __restrict__ G, int P) {
    const int idx = blockIdx.x * 256 + threadIdx.x;   // 0..65535
    float sum = 0.0f;
    for (int s = 0; s < P; ++s) sum += part[(size_t)s * (NROW * NROW) + idx];
    G[idx] = sum;
}

// ---------------------------------------------------------------------------
// Per-row: D_ij = sqrt(max(Gii + Gjj - 2 Gij, 0)), softmax over -D (j != i),
// probs = sum of softmax where labels match, row_loss = log(Z) - log(num).
// One block (256 threads) per row. sq[i] == G[i][i].
// ---------------------------------------------------------------------------
__global__ __launch_bounds__(256) void row_loss_k(const float* __restrict__ G,
                                                  const int* __restrict__ labels,
                                                  float* __restrict__ rloss) {
    const int i = blockIdx.x;
    const int j = threadIdx.x;

    const float Gii = G[i * NROW + i];
    const float Gjj = G[j * NROW + j];
    const float Gij = G[i * NROW + j];
    float d2 = fmaxf(Gii + Gjj - 2.0f * Gij, 0.0f);
    const bool diag = (j == i);
    const float s = diag ? -3.0e38f : -sqrtf(d2);

    __shared__ float red0[4], red1[4];

    // block max over 256 lanes (wave64 shuffle + cross-wave LDS)
    float m = s;
    #pragma unroll
    for (int off = 32; off; off >>= 1) m = fmaxf(m, __shfl_xor(m, off, 64));
    const int w = j >> 6;
    if ((j & 63) == 0) red0[w] = m;
    __syncthreads();
    m = fmaxf(fmaxf(red0[0], red0[1]), fmaxf(red0[2], red0[3]));

    const float p = diag ? 0.0f : expf(s - m);
    const float n = (labels[j] == labels[i]) ? p : 0.0f;

    float zs = p, ns = n;
    #pragma unroll
    for (int off = 32; off; off >>= 1) {
        zs += __shfl_xor(zs, off, 64);
        ns += __shfl_xor(ns, off, 64);
    }
    __syncthreads();   // WAR guard before reusing red0
    if ((j & 63) == 0) { red0[w] = zs; red1[w] = ns; }
    __syncthreads();
    if (j == 0) {
        const float Z = red0[0] + red0[1] + red0[2] + red0[3];
        const float N = red1[0] + red1[1] + red1[2] + red1[3];
        rloss[i] = logf(Z) - logf(N);
    }
}

// Deterministic tree-sum of 256 row losses; /200. PSD term is provably 0
// (AM-GM: log geo-mean <= log arith-mean, clipped at 0), so it's omitted.
__global__ __launch_bounds__(256) void final_k(const float* __restrict__ rloss,
                                               float* __restrict__ out) {
    __shared__ float sh[256];
    const int t = threadIdx.x;
    sh[t] = rloss[t];
    __syncthreads();
    for (int off = 128; off; off >>= 1) {
        if (t < off) sh[t] += sh[t + off];
        __syncthreads();
    }
    if (t == 0) out[0] = sh[0] * 0.005f;   // 1/200
}

extern "C" void kernel_launch(void* const* d_in, const int* in_sizes, int n_in,
                              void* d_out, int out_size, void* d_ws, size_t ws_size,
                              hipStream_t stream) {
    const float* E      = (const float*)d_in[0];
    const int*   labels = (const int*)d_in[1];
    float*       out    = (float*)d_out;

    // ws layout: G (64K floats) | rloss (256) | partials (P * 64K floats)
    float* G     = (float*)d_ws;
    float* rloss = G + NROW * NROW;
    float* part  = rloss + NROW;

    const size_t base = (size_t)(NROW * NROW + NROW) * sizeof(float);
    int P = 1;
    const int cands[7] = {64, 32, 16, 8, 4, 2, 1};
    for (int ci = 0; ci < 7; ++ci) {
        if (base + (size_t)cands[ci] * NROW * NROW * sizeof(float) <= ws_size) {
            P = cands[ci];
            break;
        }
    }
    const int Kc = DIM / P;

    gemm_pair<<<dim3(10, P), 256, 0, stream>>>(E, part, Kc);
    reduce_G <<<NROW, 256, 0, stream>>>(part, G, P);
    row_loss_k<<<NROW, 256, 0, stream>>>(G, labels, rloss);
    final_k  <<<1, 256, 0, stream>>>(rloss, out);
}

// Round 2
// 51.283 us; speedup vs baseline: 2.7896x; 2.7896x over previous
//
#include <hip/hip_runtime.h>
#include <math.h>

#define NROW 256
#define DIM  65536
#define BK   32
#define LDSP 40          // padded LDS row stride (bf16 elems): 32 + 8

typedef __attribute__((ext_vector_type(8))) short short8;
typedef __attribute__((ext_vector_type(4))) float f32x4;

__device__ __forceinline__ ushort f2bf(float f) {   // RNE fp32 -> bf16 (finite data)
    unsigned u = __builtin_bit_cast(unsigned, f);
    u += 0x7fffu + ((u >> 16) & 1u);
    return (ushort)(u >> 16);
}
__device__ __forceinline__ float bf2f(ushort h) {
    unsigned u = ((unsigned)h) << 16;
    return __builtin_bit_cast(float, u);
}

// native-layout position of G[i][j] (matches gemm epilogue store order)
__device__ __forceinline__ int gpos(int i, int j) {
    const int wid  = ((i >> 7) << 2) | (j >> 6);
    const int lane = (((i >> 2) & 3) << 4) | (j & 15);
    const int m = (i >> 4) & 7, n = (j >> 4) & 3, jr = i & 3;
    return ((wid << 6) | lane) * 128 + (((m << 2) | n) << 2) + jr;
}

// ---------------------------------------------------------------------------
// Split-K MFMA GEMM: block s computes the FULL 256x256 = E*E^T over its
// K-chunk (fp32 loaded once from HBM, converted to bf16 into LDS; A and B
// fragments both come from the same staged tile). Partial written bf16 in
// thread-native layout: part[s][tid*128 + (m*4+n)*4 + j].
// ---------------------------------------------------------------------------
__global__ __launch_bounds__(512) void gemm_mfma(const float* __restrict__ E,
                                                 ushort* __restrict__ part,
                                                 int stepsPer, int extra) {
    const int s      = blockIdx.x;
    const int step0  = s * stepsPer + (s < extra ? s : extra);
    const int nsteps = stepsPer + (s < extra ? 1 : 0);

    const int tid  = threadIdx.x;
    const int lane = tid & 63;
    const int wid  = tid >> 6;
    const int wr   = wid >> 2;          // 0..1 -> 128-row band
    const int wc   = wid & 3;           // 0..3 -> 64-col band
    const int r15  = lane & 15;
    const int kg   = (lane >> 4) * 8;   // k-group base within BK=32

    __shared__ ushort Es[2][NROW][LDSP];

    f32x4 acc[8][4];
    #pragma unroll
    for (int m = 0; m < 8; ++m)
        #pragma unroll
        for (int n = 0; n < 4; ++n) acc[m][n] = (f32x4){0.f, 0.f, 0.f, 0.f};

    // staging: thread covers row tid>>1, 16-float half (tid&1)
    const int srow  = tid >> 1;
    const int skoff = (tid & 1) * 16;
    const float* gbase = E + (size_t)srow * DIM + skoff;

    float4 v[4], vn[4];
    {   // prologue: load + stage step0 into buf 0
        const float4* p = (const float4*)(gbase + (size_t)step0 * BK);
        v[0] = p[0]; v[1] = p[1]; v[2] = p[2]; v[3] = p[3];
        ushort* d = &Es[0][srow][skoff];
        const float* f = (const float*)v;
        short8 o0, o1;
        #pragma unroll
        for (int e = 0; e < 8; ++e) { o0[e] = (short)f2bf(f[e]); o1[e] = (short)f2bf(f[8 + e]); }
        *(short8*)d = o0; *(short8*)(d + 8) = o1;
    }

    for (int t = 0; t < nsteps; ++t) {
        const int buf = t & 1;
        if (t + 1 < nsteps) {   // issue next chunk's global loads early
            const float4* p = (const float4*)(gbase + (size_t)(step0 + t + 1) * BK);
            vn[0] = p[0]; vn[1] = p[1]; vn[2] = p[2]; vn[3] = p[3];
        }
        __syncthreads();        // buf fully staged (writes from prev iter)

        short8 afrag[8], bfrag[4];
        #pragma unroll
        for (int m = 0; m < 8; ++m)
            afrag[m] = *(const short8*)&Es[buf][wr * 128 + m * 16 + r15][kg];
        #pragma unroll
        for (int n = 0; n < 4; ++n)
            bfrag[n] = *(const short8*)&Es[buf][wc * 64 + n * 16 + r15][kg];

        #pragma unroll
        for (int m = 0; m < 8; ++m)
            #pragma unroll
            for (int n = 0; n < 4; ++n)
                acc[m][n] = __builtin_amdgcn_mfma_f32_16x16x32_bf16(
                    afrag[m], bfrag[n], acc[m][n], 0, 0, 0);

        if (t + 1 < nsteps) {   // stage next chunk into the other buffer
            ushort* d = &Es[buf ^ 1][srow][skoff];
            const float* f = (const float*)vn;
            short8 o0, o1;
            #pragma unroll
            for (int e = 0; e < 8; ++e) { o0[e] = (short)f2bf(f[e]); o1[e] = (short)f2bf(f[8 + e]); }
            *(short8*)d = o0; *(short8*)(d + 8) = o1;
        }
    }

    // epilogue: 128 accs -> bf16, contiguous per-thread (fully coalesced b128)
    ushort* pp = part + (size_t)s * (NROW * NROW) + (size_t)tid * 128;
    #pragma unroll
    for (int m = 0; m < 8; ++m)
        #pragma unroll
        for (int n = 0; n < 4; n += 2) {
            short8 o;
            #pragma unroll
            for (int j = 0; j < 4; ++j) {
                o[j]     = (short)f2bf(acc[m][n][j]);
                o[4 + j] = (short)f2bf(acc[m][n + 1][j]);
            }
            *(short8*)(pp + ((m << 2) | n) * 4) = o;
        }
}

// Fixed-order sum of P bf16 partials -> Gn (fp32, native layout). Deterministic.
__global__ __launch_bounds__(256) void reduce_k(const ushort* __restrict__ part,
                                                float* __restrict__ Gn, int P) {
    const int b = blockIdx.x, t = threadIdx.x;
    const int l = t & 63, sg = t >> 6;
    const int n0 = b * 256 + l * 4;

    float a0 = 0.f, a1 = 0.f, a2 = 0.f, a3 = 0.f;
    for (int s = sg; s < P; s += 4) {
        const ushort4 u = *(const ushort4*)&part[(size_t)s * (NROW * NROW) + n0];
        a0 += bf2f(u.x); a1 += bf2f(u.y); a2 += bf2f(u.z); a3 += bf2f(u.w);
    }
    __shared__ float sh[4][256];
    sh[sg][l * 4 + 0] = a0; sh[sg][l * 4 + 1] = a1;
    sh[sg][l * 4 + 2] = a2; sh[sg][l * 4 + 3] = a3;
    __syncthreads();
    Gn[b * 256 + t] = (sh[0][t] + sh[1][t]) + (sh[2][t] + sh[3][t]);
}

// ---------------------------------------------------------------------------
// Per-row softmax loss (reads Gn through the native-layout permutation).
// ---------------------------------------------------------------------------
__global__ __launch_bounds__(256) void row_loss_k(const float* __restrict__ Gn,
                                                  const int* __restrict__ labels,
                                                  float* __restrict__ rloss) {
    const int i = blockIdx.x;
    const int j = threadIdx.x;

    const float Gii = Gn[gpos(i, i)];
    const float Gjj = Gn[gpos(j, j)];
    const float Gij = Gn[gpos(i, j)];
    const float d2 = fmaxf(Gii + Gjj - 2.0f * Gij, 0.0f);
    const bool diag = (j == i);
    const float sc = diag ? -3.0e38f : -sqrtf(d2);

    __shared__ float red0[4], red1[4];

    float m = sc;
    #pragma unroll
    for (int off = 32; off; off >>= 1) m = fmaxf(m, __shfl_xor(m, off, 64));
    const int w = j >> 6;
    if ((j & 63) == 0) red0[w] = m;
    __syncthreads();
    m = fmaxf(fmaxf(red0[0], red0[1]), fmaxf(red0[2], red0[3]));

    const float p = diag ? 0.0f : expf(sc - m);
    const float nmask = (labels[j] == labels[i]) ? p : 0.0f;

    float zs = p, ns = nmask;
    #pragma unroll
    for (int off = 32; off; off >>= 1) {
        zs += __shfl_xor(zs, off, 64);
        ns += __shfl_xor(ns, off, 64);
    }
    __syncthreads();
    if ((j & 63) == 0) { red0[w] = zs; red1[w] = ns; }
    __syncthreads();
    if (j == 0) {
        const float Z = red0[0] + red0[1] + red0[2] + red0[3];
        const float N = red1[0] + red1[1] + red1[2] + red1[3];
        rloss[i] = logf(Z) - logf(N);
    }
}

// PSD term is provably 0 (AM-GM; clip at 0), omitted.
__global__ __launch_bounds__(256) void final_k(const float* __restrict__ rloss,
                                               float* __restrict__ out) {
    __shared__ float sh[256];
    const int t = threadIdx.x;
    sh[t] = rloss[t];
    __syncthreads();
    for (int off = 128; off; off >>= 1) {
        if (t < off) sh[t] += sh[t + off];
        __syncthreads();
    }
    if (t == 0) out[0] = sh[0] * 0.005f;   // 1/200
}

extern "C" void kernel_launch(void* const* d_in, const int* in_sizes, int n_in,
                              void* d_out, int out_size, void* d_ws, size_t ws_size,
                              hipStream_t stream) {
    const float* E      = (const float*)d_in[0];
    const int*   labels = (const int*)d_in[1];
    float*       out    = (float*)d_out;

    // pick largest split-K partial count that fits ws
    const int cands[6] = {256, 128, 64, 32, 16, 8};
    int P = 8;
    for (int ci = 0; ci < 6; ++ci) {
        const size_t need = (size_t)cands[ci] * NROW * NROW * sizeof(ushort)
                          + (size_t)NROW * NROW * sizeof(float)
                          + NROW * sizeof(float);
        if (need <= ws_size) { P = cands[ci]; break; }
    }
    const int stepsTotal = DIM / BK;            // 2048
    const int stepsPer   = stepsTotal / P;
    const int extra      = stepsTotal % P;

    ushort* part  = (ushort*)d_ws;
    float*  Gn    = (float*)((char*)d_ws + (size_t)P * NROW * NROW * sizeof(ushort));
    float*  rloss = Gn + NROW * NROW;

    gemm_mfma<<<P, 512, 0, stream>>>(E, part, stepsPer, extra);
    reduce_k <<<NROW, 256, 0, stream>>>(part, Gn, P);
    row_loss_k<<<NROW, 256, 0, stream>>>(Gn, labels, rloss);
    final_k  <<<1, 256, 0, stream>>>(rloss, out);
}